// Round 2
// baseline (44729.996 us; speedup 1.0000x reference)
//
#include <hip/hip_runtime.h>
#include <math.h>

#define NT 4096      // n_train
#define MT 8192      // n_test
#define NB 128       // cholesky block
#define NBLK 32      // NT/NB
#define CGRID 256    // persistent grid (1 block/CU)

typedef unsigned short u16;
typedef short v8s __attribute__((ext_vector_type(8)));
typedef float v4f __attribute__((ext_vector_type(4)));

// ---------------- helpers ----------------
__device__ __forceinline__ float bf2f(u16 h) {
  return __uint_as_float(((unsigned)h) << 16);
}
__device__ __forceinline__ u16 f2bf(float x) {  // RNE f32->bf16
  unsigned u = __float_as_uint(x);
  u += 0x7fffu + ((u >> 16) & 1u);
  return (u16)(u >> 16);
}
__device__ __forceinline__ void split1(float x, u16& h, u16& l) {
  h = f2bf(x);
  l = f2bf(x - bf2f(h));
}
__device__ __forceinline__ float softplusf(float x) { return log1pf(expf(x)); }

__device__ __forceinline__ void load8bf(const u16* __restrict__ p, float* f) {
  ushort4 u0 = *(const ushort4*)p;
  ushort4 u1 = *(const ushort4*)(p + 4);
  f[0] = bf2f(u0.x); f[1] = bf2f(u0.y); f[2] = bf2f(u0.z); f[3] = bf2f(u0.w);
  f[4] = bf2f(u1.x); f[5] = bf2f(u1.y); f[6] = bf2f(u1.z); f[7] = bf2f(u1.w);
}

__device__ __forceinline__ float getsc(const void* p, int f32) {
  return f32 ? *(const float*)p : bf2f(*(const u16*)p);
}
__device__ __forceinline__ float getel(const void* p, int i, int f32) {
  return f32 ? ((const float*)p)[i] : bf2f(((const u16*)p)[i]);
}
__device__ __forceinline__ void load_pt(const void* xb, int idx, int f32, float* f) {
  if (f32) {
    const float4* q = (const float4*)xb;
    float4 a = q[idx * 2], b = q[idx * 2 + 1];
    f[0] = a.x; f[1] = a.y; f[2] = a.z; f[3] = a.w;
    f[4] = b.x; f[5] = b.y; f[6] = b.z; f[7] = b.w;
  } else {
    load8bf((const u16*)xb + idx * 8, f);
  }
}

// ---------------- device-scope grid barrier (persistent kernels) ----------------
// sense-free generation barrier; cnt=bar[0], gen=bar[1]. Self-restoring across
// graph replays (cnt returns to 0; gen is monotonic).
__device__ __forceinline__ void gbar(unsigned* bar) {
  __syncthreads();
  if (threadIdx.x == 0) {
    __threadfence();
    unsigned g = __hip_atomic_load(bar + 1, __ATOMIC_RELAXED, __HIP_MEMORY_SCOPE_AGENT);
    unsigned n = __hip_atomic_fetch_add(bar, 1u, __ATOMIC_ACQ_REL, __HIP_MEMORY_SCOPE_AGENT);
    if (n == (unsigned)(CGRID - 1)) {
      __hip_atomic_store(bar, 0u, __ATOMIC_RELAXED, __HIP_MEMORY_SCOPE_AGENT);
      __hip_atomic_fetch_add(bar + 1, 1u, __ATOMIC_RELEASE, __HIP_MEMORY_SCOPE_AGENT);
    } else {
      while (__hip_atomic_load(bar + 1, __ATOMIC_ACQUIRE, __HIP_MEMORY_SCOPE_AGENT) == g)
        __builtin_amdgcn_s_sleep(2);
    }
    __threadfence();
  }
  __syncthreads();
}

__global__ void detect_dtype(const u16* __restrict__ xt, int* __restrict__ flag,
                             unsigned* __restrict__ bar) {
  if (threadIdx.x == 0) {
    int f = 0;
    for (int i = 0; i < 32; i++) if (xt[i] >= 0x4000) f = 1;
    flag[0] = f;
    bar[0] = 0u;   // barrier state init (balanced protocol keeps cnt==0 thereafter)
    bar[1] = 0u;
  }
}

// ---------------- kernel-matrix builders ----------------
__global__ void build_K(const void* __restrict__ xt, const void* __restrict__ w,
                        const void* __restrict__ rls, const void* __restrict__ rvar,
                        const void* __restrict__ rnv, float* __restrict__ K,
                        const int* __restrict__ flag) {
  int f32 = flag[0];
  int j = blockIdx.x * 16 + threadIdx.x;
  int i = blockIdx.y * 16 + threadIdx.y;
  float ls  = softplusf(getsc(rls, f32));
  float var = softplusf(getsc(rvar, f32));
  float cc  = -0.5f / (ls * ls);
  float v;
  if (i == j) {
    v = var + softplusf(getsc(rnv, f32)) + 1e-6f;
  } else {
    float a[8], b[8];
    load_pt(xt, i, f32, a);
    load_pt(xt, j, f32, b);
    float d = 0.f;
#pragma unroll
    for (int q = 0; q < 8; q++) { float t = a[q] - b[q]; d += t * t; }
    v = var * expf(cc * d) * getel(w, i, f32) * getel(w, j, f32);
  }
  K[(size_t)i * NT + j] = v;
}

// Kst[j][i] = w_i * k(x_i, x_j) as split bf16 hi/lo planes [MT][NT]
__global__ void build_Kst(const void* __restrict__ xt, const void* __restrict__ xs,
                          const void* __restrict__ w, const void* __restrict__ rls,
                          const void* __restrict__ rvar,
                          u16* __restrict__ hi, u16* __restrict__ lo,
                          const int* __restrict__ flag) {
  int f32 = flag[0];
  int i = blockIdx.x * 16 + threadIdx.x;   // train (fast dim)
  int j = blockIdx.y * 16 + threadIdx.y;   // test
  float ls  = softplusf(getsc(rls, f32));
  float var = softplusf(getsc(rvar, f32));
  float cc  = -0.5f / (ls * ls);
  float a[8], b[8];
  load_pt(xt, i, f32, a);
  load_pt(xs, j, f32, b);
  float d = 0.f;
#pragma unroll
  for (int q = 0; q < 8; q++) { float t = a[q] - b[q]; d += t * t; }
  float v = getel(w, i, f32) * var * expf(cc * d);
  size_t o = (size_t)j * NT + i;
  u16 h, l; split1(v, h, l);
  hi[o] = h; lo[o] = l;
}

// ---------------- persistent Cholesky + alpha solves (1 dispatch) ----------------
// grid = 256 blocks x 256 thr, ~130KB LDS -> 1 block/CU, co-resident.
// Per kb: all blocks redundantly potrf+invert the diag block in LDS (same latency
// as one block; gives every block W locally); panel strips distributed; trailing
// tiles distributed (f32); then fwd/bwd triangular solves with 1 gbar per step.
__global__ void __launch_bounds__(256) coop_chol(
    float* __restrict__ Kf, float* __restrict__ Wall,
    u16* __restrict__ Whi, u16* __restrict__ Wlo,
    const void* __restrict__ y, float* __restrict__ rbuf,
    float* __restrict__ zbuf, float* __restrict__ abuf,
    const int* __restrict__ flag, unsigned* __restrict__ bar) {
  __shared__ float At[NB * NB];     // 64KB: potrf At / panel As / trailing As
  __shared__ float Wv[NB * 130];    // 65KB: W (padded 130) / trailing Bs (stride 68)
  __shared__ float tsv[NB];
  __shared__ float part[256];
  int tid = threadIdx.x, bid = blockIdx.x;

  for (int kb = 0; kb < NBLK; kb++) {
    int r0 = kb * NB;
    int t0 = r0 + NB;
    int rowsK = NT - t0;

    // ---- potrf + invert (redundant in every block) ----
    for (int idx = tid; idx < NB * NB; idx += 256) {
      int k = idx >> 7, i = idx & 127;
      At[idx] = Kf[(size_t)(r0 + k) * NT + r0 + i];
      Wv[k * 130 + i] = (k == i) ? 1.f : 0.f;
    }
    __syncthreads();
    for (int j = 0; j < NB; j++) {
      float inv = 1.0f / At[j * NB + j];
      int nel = (NB - 1 - j) << 7;
      for (int idx = tid; idx < nel; idx += 256) {
        int k = j + 1 + (idx >> 7);
        int i = idx & 127;
        if (i >= k) At[k * NB + i] -= At[j * NB + i] * (At[j * NB + k] * inv);
      }
      __syncthreads();
    }
    for (int t = 0; t < NB; t++) {
      float invd = 1.0f / At[t * NB + t];
      int nel = (NB - 1 - t) << 7;
      for (int idx = tid; idx < nel; idx += 256) {
        int i = t + 1 + (idx >> 7);
        int c = idx & 127;
        Wv[i * 130 + c] -= (At[t * NB + i] * invd) * Wv[t * 130 + c];
      }
      __syncthreads();
    }
    // scale W rows by 1/L[i,i] in place (every block needs it for its panel strips)
    for (int idx = tid; idx < NB * NB; idx += 256) {
      int i = idx >> 7, c = idx & 127;
      Wv[i * 130 + c] *= 1.0f / sqrtf(At[i * NB + i]);
    }
    __syncthreads();
    if (bid == 0) {   // write L diag, Wall f32, W planes
      for (int idx = tid; idx < NB * NB; idx += 256) {
        int k = idx >> 7, i = idx & 127;
        if (i >= k) {
          float s = sqrtf(At[k * NB + k]);
          Kf[(size_t)(r0 + i) * NT + r0 + k] = (i == k) ? s : At[k * NB + i] / s;
        }
        float wv = Wv[k * 130 + i];
        Wall[(size_t)kb * NB * NB + idx] = wv;
        u16 h, l; split1(wv, h, l);
        Whi[(size_t)kb * NB * NB + idx] = h;
        Wlo[(size_t)kb * NB * NB + idx] = l;
      }
    }
    __syncthreads();

    // ---- panel: L21(strip) = A21(strip) @ W^T, strips of 64 rows ----
    if (rowsK > 0 && bid < (rowsK >> 6)) {
      int m0 = t0 + bid * 64;
      // stage A strip k-major: At[k*68+row]
      for (int ch = tid; ch < 64 * 32; ch += 256) {
        int row = ch >> 5, c4 = ch & 31;
        float4 v = *(const float4*)&Kf[(size_t)(m0 + row) * NT + r0 + c4 * 4];
        At[(c4 * 4 + 0) * 68 + row] = v.x; At[(c4 * 4 + 1) * 68 + row] = v.y;
        At[(c4 * 4 + 2) * 68 + row] = v.z; At[(c4 * 4 + 3) * 68 + row] = v.w;
      }
      __syncthreads();
      float pa[8][4];
#pragma unroll
      for (int r = 0; r < 8; r++)
#pragma unroll
        for (int c = 0; c < 4; c++) pa[r][c] = 0.f;
      int rr0 = (tid >> 5) * 8, cc0 = (tid & 31) * 4;
      for (int k = 0; k < NB; k++) {
        float a0[8], b0[4];
        *(float4*)&a0[0] = *(const float4*)&At[k * 68 + rr0];
        *(float4*)&a0[4] = *(const float4*)&At[k * 68 + rr0 + 4];
        b0[0] = Wv[(cc0 + 0) * 130 + k]; b0[1] = Wv[(cc0 + 1) * 130 + k];
        b0[2] = Wv[(cc0 + 2) * 130 + k]; b0[3] = Wv[(cc0 + 3) * 130 + k];
#pragma unroll
        for (int r = 0; r < 8; r++)
#pragma unroll
          for (int c = 0; c < 4; c++) pa[r][c] += a0[r] * b0[c];
      }
#pragma unroll
      for (int r = 0; r < 8; r++) {
        float4 o; o.x = pa[r][0]; o.y = pa[r][1]; o.z = pa[r][2]; o.w = pa[r][3];
        *(float4*)&Kf[(size_t)(m0 + rr0 + r) * NT + r0 + cc0] = o;
      }
    }
    gbar(bar);

    // ---- trailing: A22 -= L21 @ L21^T (tiles 128x64, lower only, f32) ----
    if (rowsK > 0) {
      int nmT = rowsK >> 7, nnT = rowsK >> 6;
      int ntile = nmT * nnT;
      for (int ti = bid; ti < ntile; ti += CGRID) {
        int m = ti / nnT, n = ti % nnT;
        int m0 = t0 + m * 128, n0 = t0 + n * 64;
        if (n0 > m0 + 127) continue;
        __syncthreads();
        for (int ch = tid; ch < 128 * 32; ch += 256) {     // A: At[k*128+row]
          int row = ch >> 5, c4 = ch & 31;
          float4 v = *(const float4*)&Kf[(size_t)(m0 + row) * NT + r0 + c4 * 4];
          At[(c4 * 4 + 0) * 128 + row] = v.x; At[(c4 * 4 + 1) * 128 + row] = v.y;
          At[(c4 * 4 + 2) * 128 + row] = v.z; At[(c4 * 4 + 3) * 128 + row] = v.w;
        }
        for (int ch = tid; ch < 64 * 32; ch += 256) {      // B: Wv[k*68+n]
          int nn_ = ch >> 5, c4 = ch & 31;
          float4 v = *(const float4*)&Kf[(size_t)(n0 + nn_) * NT + r0 + c4 * 4];
          Wv[(c4 * 4 + 0) * 68 + nn_] = v.x; Wv[(c4 * 4 + 1) * 68 + nn_] = v.y;
          Wv[(c4 * 4 + 2) * 68 + nn_] = v.z; Wv[(c4 * 4 + 3) * 68 + nn_] = v.w;
        }
        __syncthreads();
        float ac[8][4];
#pragma unroll
        for (int r = 0; r < 8; r++)
#pragma unroll
          for (int c = 0; c < 4; c++) ac[r][c] = 0.f;
        int ty = tid >> 4, tx = tid & 15;
        for (int k = 0; k < 128; k++) {
          float a0[8], b0[4];
          *(float4*)&a0[0] = *(const float4*)&At[k * 128 + ty * 8];
          *(float4*)&a0[4] = *(const float4*)&At[k * 128 + ty * 8 + 4];
          *(float4*)&b0[0] = *(const float4*)&Wv[k * 68 + tx * 4];
#pragma unroll
          for (int r = 0; r < 8; r++)
#pragma unroll
            for (int c = 0; c < 4; c++) ac[r][c] += a0[r] * b0[c];
        }
#pragma unroll
        for (int r = 0; r < 8; r++) {
          float* cp = &Kf[(size_t)(m0 + ty * 8 + r) * NT + n0 + tx * 4];
          float4 o = *(const float4*)cp;
          o.x -= ac[r][0]; o.y -= ac[r][1]; o.z -= ac[r][2]; o.w -= ac[r][3];
          *(float4*)cp = o;
        }
      }
    }
    gbar(bar);
  }

  // ---- alpha solves ----
  int f32 = flag[0];
  for (int i = bid * 256 + tid; i < NT; i += CGRID * 256) rbuf[i] = getel(y, i, f32);
  gbar(bar);

  // forward: z = L^{-1} y
  for (int kb = 0; kb < NBLK; kb++) {
    int r0 = kb * NB;
    {
      int row = tid >> 1, half = tid & 1;
      const float* Wr = Wall + (size_t)kb * NB * NB + row * NB + half * 64;
      const float* rv = rbuf + r0 + half * 64;
      float acc = 0.f;
#pragma unroll
      for (int c = 0; c < 64; c += 4) {
        float4 wv4 = *(const float4*)&Wr[c];
        float4 xv = *(const float4*)&rv[c];
        acc += wv4.x * xv.x + wv4.y * xv.y + wv4.z * xv.z + wv4.w * xv.w;
      }
      part[tid] = acc;
      __syncthreads();
      if (half == 0) tsv[row] = part[tid] + part[tid + 1];
      __syncthreads();
    }
    if (bid == 0 && tid < NB) zbuf[r0 + tid] = tsv[tid];
    int t0s = r0 + NB;
    int nst = (NT - t0s) >> 6;
    if (bid < nst) {
      int base = t0s + bid * 64;
      int wv_ = tid >> 6, lane = tid & 63;
      for (int rr = wv_; rr < 64; rr += 4) {
        int row = base + rr;
        const float* Lr = Kf + (size_t)row * NT + r0;
        float acc = Lr[lane] * tsv[lane] + Lr[lane + 64] * tsv[lane + 64];
#pragma unroll
        for (int off = 32; off > 0; off >>= 1) acc += __shfl_down(acc, off, 64);
        if (lane == 0) rbuf[row] -= acc;
      }
    }
    gbar(bar);
  }

  // backward: alpha = L^{-T} z
  for (int kb = NBLK - 1; kb >= 0; kb--) {
    int r0 = kb * NB;
    {
      int col = tid & 127, half = tid >> 7;
      const float* Wb = Wall + (size_t)kb * NB * NB;
      float acc = 0.f;
#pragma unroll 4
      for (int rr = half * 64; rr < half * 64 + 64; rr++)
        acc += Wb[rr * NB + col] * zbuf[r0 + rr];
      part[tid] = acc;
      __syncthreads();
      if (half == 0) tsv[col] = part[tid] + part[tid + 128];
      __syncthreads();
    }
    if (bid == 0 && tid < NB) abuf[r0 + tid] = tsv[tid];
    if (bid < kb) {
      int col = bid * NB + (tid & 127);
      int half = tid >> 7;
      float acc = 0.f;
#pragma unroll 4
      for (int jr = half * 64; jr < half * 64 + 64; jr++)
        acc += Kf[(size_t)(r0 + jr) * NT + col] * tsv[jr];
      part[tid] = acc;
      __syncthreads();
      if (half == 0) zbuf[col] -= part[tid] + part[tid + 128];
    }
    gbar(bar);
  }
}

// ---------------- MFMA quad-tile inner (validated round-1 fragment math) ----------------
__device__ __forceinline__ void mfma_tile(const u16* __restrict__ LAh, const u16* __restrict__ LAl,
                                          const u16* __restrict__ LBh, const u16* __restrict__ LBl,
                                          v4f acc[4][4], int wr, int wc, int lr, int lk) {
#pragma unroll
  for (int ks = 0; ks < 2; ks++) {
    v8s afh[4], afl[4], bfh[4], bfl[4];
#pragma unroll
    for (int mi = 0; mi < 4; mi++) {
      int row = wr * 64 + mi * 16 + lr;
      int sl = (ks * 4 + lk) ^ (row & 7);
      afh[mi] = *(const v8s*)&LAh[row * 64 + sl * 8];
      afl[mi] = *(const v8s*)&LAl[row * 64 + sl * 8];
    }
#pragma unroll
    for (int ni = 0; ni < 4; ni++) {
      int row = wc * 64 + ni * 16 + lr;
      int sl = (ks * 4 + lk) ^ (row & 7);
      bfh[ni] = *(const v8s*)&LBh[row * 64 + sl * 8];
      bfl[ni] = *(const v8s*)&LBl[row * 64 + sl * 8];
    }
#pragma unroll
    for (int mi = 0; mi < 4; mi++)
#pragma unroll
      for (int ni = 0; ni < 4; ni++) {
        acc[mi][ni] = __builtin_amdgcn_mfma_f32_16x16x32_bf16(afh[mi], bfh[ni], acc[mi][ni], 0, 0, 0);
        acc[mi][ni] = __builtin_amdgcn_mfma_f32_16x16x32_bf16(afh[mi], bfl[ni], acc[mi][ni], 0, 0, 0);
        acc[mi][ni] = __builtin_amdgcn_mfma_f32_16x16x32_bf16(afl[mi], bfh[ni], acc[mi][ni], 0, 0, 0);
      }
  }
}

// ---------------- persistent mu + TRSM of Vt (1 dispatch) ----------------
// 512 thr (8 waves), tiles BM=256 x BN=128, K-step 64, split-bf16 MFMA.
__global__ void __launch_bounds__(512) coop_trsm(
    u16* __restrict__ Vthi, u16* __restrict__ Vtlo,
    const u16* __restrict__ Whi, const u16* __restrict__ Wlo,
    const float* __restrict__ Kf, const float* __restrict__ alpha,
    float* __restrict__ mu, unsigned* __restrict__ bar) {
  __shared__ u16 LAh[256 * 64], LAl[256 * 64];   // 64KB
  __shared__ u16 LBh[128 * 64], LBl[128 * 64];   // 32KB
  int tid = threadIdx.x, bid = blockIdx.x;
  int lane = tid & 63, wv = tid >> 6;

  // ---- mu[j] = dot(Kst[j], alpha) (original planes, before overwrite) ----
  for (int j = bid * 8 + wv; j < MT; j += CGRID * 8) {
    const u16* ph = Vthi + (size_t)j * NT;
    const u16* pl = Vtlo + (size_t)j * NT;
    float s = 0.f;
    for (int c = lane * 4; c < NT; c += 256) {
      ushort4 h = *(const ushort4*)&ph[c];
      ushort4 l = *(const ushort4*)&pl[c];
      float4 a = *(const float4*)&alpha[c];
      s += (bf2f(h.x) + bf2f(l.x)) * a.x + (bf2f(h.y) + bf2f(l.y)) * a.y
         + (bf2f(h.z) + bf2f(l.z)) * a.z + (bf2f(h.w) + bf2f(l.w)) * a.w;
    }
#pragma unroll
    for (int off = 32; off > 0; off >>= 1) s += __shfl_down(s, off, 64);
    if (lane == 0) mu[j] = s;
  }
  gbar(bar);

  int wr = wv >> 1, wc = wv & 1;    // 8 waves -> 4x2 quadrants of 256x128
  int lr = lane & 15, lk = lane >> 4;
  v4f zero = {0.f, 0.f, 0.f, 0.f};

  for (int kb = 0; kb < NBLK; kb++) {
    int r0 = kb * NB;
    // ---- z-phase: Vt[:,kb] = Vt[:,kb] @ W_kb^T (in place; strips of 256 rows) ----
    if (bid < MT / 256) {
      int m0 = bid * 256;
      v4f acc[4][4];
#pragma unroll
      for (int mi = 0; mi < 4; mi++)
#pragma unroll
        for (int ni = 0; ni < 4; ni++) acc[mi][ni] = zero;
      for (int kt = 0; kt < 2; kt++) {
        int k0 = r0 + kt * 64;
        __syncthreads();
#pragma unroll
        for (int p = 0; p < 4; p++) {
          int ch = p * 512 + tid;
          int row = ch >> 3, sl = ch & 7;
          size_t o = (size_t)(m0 + row) * NT + k0 + sl * 8;
          int off = row * 64 + ((sl ^ (row & 7)) * 8);
          *(int4*)&LAh[off] = *(const int4*)(Vthi + o);
          *(int4*)&LAl[off] = *(const int4*)(Vtlo + o);
        }
#pragma unroll
        for (int p = 0; p < 2; p++) {
          int ch = p * 512 + tid;
          int row = ch >> 3, sl = ch & 7;
          size_t o = (size_t)kb * NB * NB + row * NB + kt * 64 + sl * 8;
          int off = row * 64 + ((sl ^ (row & 7)) * 8);
          *(int4*)&LBh[off] = *(const int4*)(Whi + o);
          *(int4*)&LBl[off] = *(const int4*)(Wlo + o);
        }
        __syncthreads();
        mfma_tile(LAh, LAl, LBh, LBl, acc, wr, wc, lr, lk);
      }
#pragma unroll
      for (int mi = 0; mi < 4; mi++)
#pragma unroll
        for (int r = 0; r < 4; r++) {
          int grow = m0 + wr * 64 + mi * 16 + lk * 4 + r;
#pragma unroll
          for (int ni = 0; ni < 4; ni++) {
            int gcol = r0 + wc * 64 + ni * 16 + lr;
            size_t o = (size_t)grow * NT + gcol;
            u16 h, l; split1(acc[mi][ni][r], h, l);
            Vthi[o] = h; Vtlo[o] = l;
          }
        }
    }
    gbar(bar);

    // ---- trailing: Vt[:,t0+] -= Vt[:,kb] @ L21^T (B from f32 Kf, split on the fly) ----
    int t0 = (kb + 1) * NB, rowsT = NT - t0;
    if (rowsT > 0) {
      int nn = rowsT >> 7;
      int ntile = (MT / 256) * nn;
      for (int ti = bid; ti < ntile; ti += CGRID) {
        int m = ti % (MT / 256), n = ti / (MT / 256);
        int m0 = m * 256, n0 = t0 + n * 128;
        v4f acc[4][4];
#pragma unroll
        for (int mi = 0; mi < 4; mi++)
#pragma unroll
          for (int ni = 0; ni < 4; ni++) acc[mi][ni] = zero;
        for (int kt = 0; kt < 2; kt++) {
          int k0 = r0 + kt * 64;
          __syncthreads();
#pragma unroll
          for (int p = 0; p < 4; p++) {
            int ch = p * 512 + tid;
            int row = ch >> 3, sl = ch & 7;
            size_t o = (size_t)(m0 + row) * NT + k0 + sl * 8;
            int off = row * 64 + ((sl ^ (row & 7)) * 8);
            *(int4*)&LAh[off] = *(const int4*)(Vthi + o);
            *(int4*)&LAl[off] = *(const int4*)(Vtlo + o);
          }
#pragma unroll
          for (int p = 0; p < 4; p++) {
            int ch = p * 512 + tid;
            int row = ch >> 4, f4 = ch & 15;
            float4 v = *(const float4*)&Kf[(size_t)(n0 + row) * NT + k0 + f4 * 4];
            ushort4 h, l;
            split1(v.x, h.x, l.x); split1(v.y, h.y, l.y);
            split1(v.z, h.z, l.z); split1(v.w, h.w, l.w);
            int sl = f4 >> 1, half = f4 & 1;
            int off = row * 64 + ((sl ^ (row & 7)) * 8) + half * 4;
            *(ushort4*)&LBh[off] = h;
            *(ushort4*)&LBl[off] = l;
          }
          __syncthreads();
          mfma_tile(LAh, LAl, LBh, LBl, acc, wr, wc, lr, lk);
        }
#pragma unroll
        for (int mi = 0; mi < 4; mi++)
#pragma unroll
          for (int r = 0; r < 4; r++) {
            int grow = m0 + wr * 64 + mi * 16 + lk * 4 + r;
#pragma unroll
            for (int ni = 0; ni < 4; ni++) {
              int gcol = n0 + wc * 64 + ni * 16 + lr;
              size_t o = (size_t)grow * NT + gcol;
              float nv = (bf2f(Vthi[o]) + bf2f(Vtlo[o])) - acc[mi][ni][r];
              u16 h, l; split1(nv, h, l);
              Vthi[o] = h; Vtlo[o] = l;
            }
          }
      }
    }
    gbar(bar);
  }
}

// ---------------- cov = Kss - v^T v (round-1 validated kernel, MODE2) ----------------
template<int MODE, int BF32>
__global__ void __launch_bounds__(256) mm_bf16(
    const u16* __restrict__ Ah, const u16* __restrict__ Al, int lda,
    const u16* __restrict__ Bh, const u16* __restrict__ Bl,
    const float* __restrict__ Bf, int ldb,
    u16* __restrict__ Chi, u16* __restrict__ Clo, float* __restrict__ Cf,
    int ldc, int Kdim,
    const void* __restrict__ xs, const void* __restrict__ rls,
    const void* __restrict__ rvar, const int* __restrict__ flag) {
  int c0 = blockIdx.x * 128;
  int r0 = blockIdx.y * 128;
  if (MODE == 2 && r0 < c0) return;
  __shared__ u16 L[4][128 * 64];
  int tid = threadIdx.x;
  int lane = tid & 63, wv = tid >> 6;
  int wr = wv >> 1, wc = wv & 1;
  int lr = lane & 15, lk = lane >> 4;

  v4f acc[4][4];
  v4f zero = {0.f, 0.f, 0.f, 0.f};
#pragma unroll
  for (int mi = 0; mi < 4; mi++)
#pragma unroll
    for (int ni = 0; ni < 4; ni++) acc[mi][ni] = zero;

  for (int kt = 0; kt < Kdim; kt += 64) {
    int4 rga[8], rgb[8];
#pragma unroll
    for (int p = 0; p < 4; p++) {
      int ch = p * 256 + tid;
      int row = ch >> 3, sl = ch & 7;
      size_t o = (size_t)(r0 + row) * lda + kt + sl * 8;
      rga[p]     = *(const int4*)(Ah + o);
      rga[p + 4] = *(const int4*)(Al + o);
    }
    if (BF32 == 0) {
#pragma unroll
      for (int p = 0; p < 4; p++) {
        int ch = p * 256 + tid;
        int row = ch >> 3, sl = ch & 7;
        size_t o = (size_t)(c0 + row) * ldb + kt + sl * 8;
        rgb[p]     = *(const int4*)(Bh + o);
        rgb[p + 4] = *(const int4*)(Bl + o);
      }
    } else {
#pragma unroll
      for (int p = 0; p < 8; p++) {
        int ch = p * 256 + tid;
        int row = ch >> 4, f4 = ch & 15;
        rgb[p] = *(const int4*)(Bf + (size_t)(c0 + row) * ldb + kt + f4 * 4);
      }
    }
    __syncthreads();
#pragma unroll
    for (int p = 0; p < 4; p++) {
      int ch = p * 256 + tid;
      int row = ch >> 3, sl = ch & 7;
      int off = row * 64 + ((sl ^ (row & 7)) * 8);
      *(int4*)&L[0][off] = rga[p];
      *(int4*)&L[1][off] = rga[p + 4];
      if (BF32 == 0) {
        *(int4*)&L[2][off] = rgb[p];
        *(int4*)&L[3][off] = rgb[p + 4];
      }
    }
    if (BF32 == 1) {
#pragma unroll
      for (int p = 0; p < 8; p++) {
        int ch = p * 256 + tid;
        int row = ch >> 4, f4 = ch & 15;
        const float* v = (const float*)&rgb[p];
        ushort4 h, l;
        split1(v[0], h.x, l.x); split1(v[1], h.y, l.y);
        split1(v[2], h.z, l.z); split1(v[3], h.w, l.w);
        int sl = f4 >> 1, half = f4 & 1;
        int off = row * 64 + ((sl ^ (row & 7)) * 8) + half * 4;
        *(ushort4*)&L[2][off] = h;
        *(ushort4*)&L[3][off] = l;
      }
    }
    __syncthreads();
    mfma_tile(&L[0][0], &L[1][0], &L[2][0], &L[3][0], acc, wr, wc, lr, lk);
    __syncthreads();
  }

  if (MODE == 2) {
    int f32 = flag[0];
    float ls  = softplusf(getsc(rls, f32));
    float var = softplusf(getsc(rvar, f32));
    float cc  = -0.5f / (ls * ls);
#pragma unroll
    for (int mi = 0; mi < 4; mi++) {
#pragma unroll
      for (int r = 0; r < 4; r++) {
        int grow = r0 + wr * 64 + mi * 16 + lk * 4 + r;
        float xr[8];
        load_pt(xs, grow, f32, xr);
#pragma unroll
        for (int ni = 0; ni < 4; ni++) {
          int gcol = c0 + wc * 64 + ni * 16 + lr;
          float xc[8];
          load_pt(xs, gcol, f32, xc);
          float d = 0.f;
#pragma unroll
          for (int q = 0; q < 8; q++) { float t = xr[q] - xc[q]; d += t * t; }
          float kss = var * expf(cc * d);
          if (grow == gcol) kss += 1e-6f;
          float ov = kss - acc[mi][ni][r];
          Cf[(size_t)grow * ldc + gcol] = ov;
          if (grow > gcol) Cf[(size_t)gcol * ldc + grow] = ov;
        }
      }
    }
  } else {
#pragma unroll
    for (int mi = 0; mi < 4; mi++) {
#pragma unroll
      for (int r = 0; r < 4; r++) {
        int grow = r0 + wr * 64 + mi * 16 + lk * 4 + r;
#pragma unroll
        for (int ni = 0; ni < 4; ni++) {
          int gcol = c0 + wc * 64 + ni * 16 + lr;
          size_t o = (size_t)grow * ldc + gcol;
          float nv;
          if (MODE == 0) {
            nv = acc[mi][ni][r];
          } else {
            nv = (bf2f(Chi[o]) + bf2f(Clo[o])) - acc[mi][ni][r];
          }
          u16 h, l; split1(nv, h, l);
          Chi[o] = h; Clo[o] = l;
        }
      }
    }
  }
}

// ---------------- host ----------------
extern "C" void kernel_launch(void* const* d_in, const int* in_sizes, int n_in,
                              void* d_out, int out_size, void* d_ws, size_t ws_size,
                              hipStream_t stream) {
  (void)in_sizes; (void)n_in; (void)out_size; (void)ws_size;
  const void* xt  = d_in[0];
  const void* y   = d_in[1];
  const void* w   = d_in[2];
  const void* xs  = d_in[3];
  const void* rls = d_in[4];
  const void* rva = d_in[5];
  const void* rnv = d_in[6];

  float* mu_out  = (float*)d_out;        // [MT] f32
  float* cov_out = mu_out + MT;          // [MT*MT] f32

  float* Kf   = (float*)d_ws;                              // NT*NT f32
  float* Wall = Kf + (size_t)NT * NT;                      // NBLK*NB*NB f32
  float* S    = Wall + (size_t)NBLK * NB * NB;             // (unused, layout keep)
  float* rbuf = S + (size_t)(NT - NB) * NB;                // NT
  float* zbuf = rbuf + NT;                                 // NT
  float* abuf = zbuf + NT;                                 // NT
  int*   flag = (int*)(abuf + NT);                         // dtype flag
  unsigned* bar = (unsigned*)(flag + 4);                   // grid barrier {cnt,gen}
  u16* Whi  = (u16*)(flag + 8);                            // NBLK*NB*NB bf16
  u16* Wlo  = Whi + (size_t)NBLK * NB * NB;
  u16* Vthi = Wlo + (size_t)NBLK * NB * NB;                // [MT][NT] bf16
  u16* Vtlo = Vthi + (size_t)MT * NT;                      // [MT][NT] bf16

  detect_dtype<<<1, 64, 0, stream>>>((const u16*)xt, flag, bar);
  build_K<<<dim3(NT / 16, NT / 16), dim3(16, 16), 0, stream>>>(xt, w, rls, rva, rnv, Kf, flag);
  build_Kst<<<dim3(NT / 16, MT / 16), dim3(16, 16), 0, stream>>>(xt, xs, w, rls, rva,
                                                                 Vthi, Vtlo, flag);
  coop_chol<<<CGRID, 256, 0, stream>>>(Kf, Wall, Whi, Wlo, y, rbuf, zbuf, abuf, flag, bar);
  coop_trsm<<<CGRID, 512, 0, stream>>>(Vthi, Vtlo, Whi, Wlo, Kf, abuf, mu_out, bar);
  mm_bf16<2, 0><<<dim3(MT / 128, MT / 128), 256, 0, stream>>>(
      Vthi, Vtlo, NT, Vthi, Vtlo, nullptr, NT,
      nullptr, nullptr, cov_out, MT, NT,
      xs, rls, rva, flag);
}